// Round 11
// baseline (231.961 us; speedup 1.0000x reference)
//
#include <hip/hip_runtime.h>

#define TT 100
#define HH 100
#define NL 5
#define NOUT 10
#define CC 10
#define NC (TT / CC)
#define RW 64   // dwords per sliced row: 4 slices x 16 dwords (13 data + 3 pad)
#define NTH 448 // 7 waves; act lanes = 400

typedef _Float16 h2f __attribute__((ext_vector_type(2)));

__device__ __forceinline__ float sigm(float x) { return 1.f / (1.f + __expf(-x)); }

__device__ __forceinline__ float fdot2u(unsigned a, unsigned b, float c) {
#if __has_builtin(__builtin_amdgcn_fdot2)
  return __builtin_amdgcn_fdot2(__builtin_bit_cast(h2f, a),
                                __builtin_bit_cast(h2f, b), c, false);
#else
  float d;
  asm("v_dot2_f32_f16 %0, %1, %2, %3" : "=v"(d) : "v"(a), "v"(b), "v"(c));
  return d;
#endif
}

__device__ __forceinline__ unsigned pk16(float lo, float hi) {
  _Float16 l = (_Float16)lo, h = (_Float16)hi;
  return (unsigned)__builtin_bit_cast(unsigned short, l) |
         ((unsigned)__builtin_bit_cast(unsigned short, h) << 16);
}

// quad all-reduce sum via DPP quad_perm (VALU pipe; no LDS, no readlane)
__device__ __forceinline__ float qred(float p) {
  int t = __builtin_amdgcn_update_dpp(0, __builtin_bit_cast(int, p), 0xB1, 0xF,
                                      0xF, true);
  p += __builtin_bit_cast(float, t);
  t = __builtin_amdgcn_update_dpp(0, __builtin_bit_cast(int, p), 0x4E, 0xF, 0xF,
                                  true);
  p += __builtin_bit_cast(float, t);
  return p;
}

#define R13(M) M(0) M(1) M(2) M(3) M(4) M(5) M(6) M(7) M(8) M(9) M(10) M(11) M(12)

// AGPR residency (proven R8). AWR volatile (init once); ARD pure for scheduling.
#define AWR(D, S) asm volatile("v_accvgpr_write_b32 %0, %1" : "=a"(D) : "v"(S));
#define ARD(D, S) asm("v_accvgpr_read_b32 %0, %1" : "=v"(D) : "a"(S));

// ---- pre-kernel: fp32 input -> sliced f16 layout [t][q:4][16 dw] in xst slot 0
__global__ void pack_x0(const float* __restrict__ in, unsigned* __restrict__ x0) {
  for (int idx = blockIdx.x * 512 + threadIdx.x; idx < TT * RW;
       idx += gridDim.x * 512) {
    int t = idx / RW, d = idx & (RW - 1);
    int q = d >> 4, m = d & 15;
    unsigned v = 0u;
    int k0 = 26 * q + 2 * m;
    if (m < 13 && k0 < 100) {  // k0 even -> k0+1 <= 99 valid
      v = pk16(in[t * HH + k0], in[t * HH + k0 + 1]);
    }
    x0[idx] = v;
  }
}

// ---- main: one block per layer (R8 skeleton verbatim for handoff/publish).
// Quad j = element j; lane q computes 26-wide k-slice of ALL 4 gates.
// Per step per lane: 8 ds_read (own slices of h,x) + 104 fdot2; gate totals
// via 8-op DPP quad-reduce. Removes R8's redundant per-wave full-vector reads.
__global__ __attribute__((amdgpu_flat_work_group_size(NTH, NTH),
                          amdgpu_waves_per_eu(2, 2)))
void lstm_pipe_kernel(
    const float* __restrict__ Wih,   // [L, 4H, H]
    const float* __restrict__ Whh,   // [L, 4H, H]
    const float* __restrict__ bih,   // [L, 4H]
    const float* __restrict__ bhh,   // [L, 4H]
    const float* __restrict__ Wout,  // [OUT, H]
    const float* __restrict__ bout,  // [OUT]
    float* __restrict__ out,         // [T, OUT]
    int* __restrict__ flags,         // [L-1, NC]
    unsigned* __restrict__ xst)      // [NL][TT][RW] sliced f16; slot l = input of layer l
{
  __shared__ __align__(16) unsigned xh32[CC * RW];   // x chunk, sliced f16
  __shared__ __align__(16) unsigned och32[CC * RW];  // publish chunk, sliced f16
  __shared__ __align__(16) unsigned hb32[2 * RW];    // h dbuf, sliced f16
  __shared__ __align__(16) float ochf[CC * HH];      // layer-4 h, fp32

  const int l = blockIdx.x;
  const int tid = threadIdx.x;
  const int j = tid >> 2;  // element 0..99 (act)
  const int q = tid & 3;   // k-slice 0..3
  const bool act = (tid < 400);
  const int hwpos = (j / 26) * 32 + (j % 26);  // sliced half-position of h[j]

  // ---- 104 AGPR weight slots: H{gate}_{m} = Whh slice dword, I* = Wih ----
#define DECLM(m) unsigned H0_##m, H1_##m, H2_##m, H3_##m, \
                          I0_##m, I1_##m, I2_##m, I3_##m;
  R13(DECLM)

  float b0 = 0.f, b1 = 0.f, b2 = 0.f, b3 = 0.f;
  if (act) {
    const int kq = 26 * q;
    const float* ph0 = Whh + (size_t)(l * 400 + 0 * 100 + j) * 100 + kq;
    const float* ph1 = Whh + (size_t)(l * 400 + 1 * 100 + j) * 100 + kq;
    const float* ph2 = Whh + (size_t)(l * 400 + 2 * 100 + j) * 100 + kq;
    const float* ph3 = Whh + (size_t)(l * 400 + 3 * 100 + j) * 100 + kq;
    const float* pi0 = Wih + (size_t)(l * 400 + 0 * 100 + j) * 100 + kq;
    const float* pi1 = Wih + (size_t)(l * 400 + 1 * 100 + j) * 100 + kq;
    const float* pi2 = Wih + (size_t)(l * 400 + 2 * 100 + j) * 100 + kq;
    const float* pi3 = Wih + (size_t)(l * 400 + 3 * 100 + j) * 100 + kq;
#define LDM(m)                                                           \
    {                                                                    \
      const bool ok = (kq + 2 * (m)) < 100;                              \
      float2 f; unsigned u;                                              \
      f = ok ? *(const float2*)(ph0 + 2 * (m)) : make_float2(0.f, 0.f);  \
      u = pk16(f.x, f.y); AWR(H0_##m, u)                                 \
      f = ok ? *(const float2*)(ph1 + 2 * (m)) : make_float2(0.f, 0.f);  \
      u = pk16(f.x, f.y); AWR(H1_##m, u)                                 \
      f = ok ? *(const float2*)(ph2 + 2 * (m)) : make_float2(0.f, 0.f);  \
      u = pk16(f.x, f.y); AWR(H2_##m, u)                                 \
      f = ok ? *(const float2*)(ph3 + 2 * (m)) : make_float2(0.f, 0.f);  \
      u = pk16(f.x, f.y); AWR(H3_##m, u)                                 \
      f = ok ? *(const float2*)(pi0 + 2 * (m)) : make_float2(0.f, 0.f);  \
      u = pk16(f.x, f.y); AWR(I0_##m, u)                                 \
      f = ok ? *(const float2*)(pi1 + 2 * (m)) : make_float2(0.f, 0.f);  \
      u = pk16(f.x, f.y); AWR(I1_##m, u)                                 \
      f = ok ? *(const float2*)(pi2 + 2 * (m)) : make_float2(0.f, 0.f);  \
      u = pk16(f.x, f.y); AWR(I2_##m, u)                                 \
      f = ok ? *(const float2*)(pi3 + 2 * (m)) : make_float2(0.f, 0.f);  \
      u = pk16(f.x, f.y); AWR(I3_##m, u)                                 \
    }
    R13(LDM)
    if (q == 0) {  // biases used only post-reduce by lane q==0
      b0 = bih[l * 400 + 0 * 100 + j] + bhh[l * 400 + 0 * 100 + j];
      b1 = bih[l * 400 + 1 * 100 + j] + bhh[l * 400 + 1 * 100 + j];
      b2 = bih[l * 400 + 2 * 100 + j] + bhh[l * 400 + 2 * 100 + j];
      b3 = bih[l * 400 + 3 * 100 + j] + bhh[l * 400 + 3 * 100 + j];
    }
  }

  // one-time zero: h dbuf (incl pads) + entire publish buffer (pads stay 0)
  if (tid < 2 * RW) hb32[tid] = 0u;
  if (tid < 160) ((uint4*)och32)[tid] = make_uint4(0u, 0u, 0u, 0u);
  float c = 0.f;
  __syncthreads();

  for (int ch = 0; ch < NC; ++ch) {
    // ---- acquire x chunk into LDS (verbatim R8 protocol) ----
    if (l > 0) {
      if (tid == 0) {
        const int* fl = flags + (l - 1) * NC + ch;
        while (__hip_atomic_load(fl, __ATOMIC_ACQUIRE, __HIP_MEMORY_SCOPE_AGENT) == 0)
          __builtin_amdgcn_s_sleep(1);
      }
      __syncthreads();
    }
    {
      const uint4* src = (const uint4*)(xst + ((size_t)l * TT + ch * CC) * RW);
      if (tid < 160) ((uint4*)xh32)[tid] = src[tid];
    }

    // ---- CC recurrent steps: sliced reads + AGPR dots + DPP reduce ----
#define GPART(gg, P)                                     \
    {                                                    \
      unsigned w; float p = 0.f, px = 0.f;               \
      ARD(w, H##gg##_0)  p = fdot2u(w, ha.x, p);         \
      ARD(w, H##gg##_1)  p = fdot2u(w, ha.y, p);         \
      ARD(w, H##gg##_2)  p = fdot2u(w, ha.z, p);         \
      ARD(w, H##gg##_3)  p = fdot2u(w, ha.w, p);         \
      ARD(w, H##gg##_4)  p = fdot2u(w, hbv.x, p);        \
      ARD(w, H##gg##_5)  p = fdot2u(w, hbv.y, p);        \
      ARD(w, H##gg##_6)  p = fdot2u(w, hbv.z, p);        \
      ARD(w, H##gg##_7)  p = fdot2u(w, hbv.w, p);        \
      ARD(w, H##gg##_8)  p = fdot2u(w, hcv.x, p);        \
      ARD(w, H##gg##_9)  p = fdot2u(w, hcv.y, p);        \
      ARD(w, H##gg##_10) p = fdot2u(w, hcv.z, p);        \
      ARD(w, H##gg##_11) p = fdot2u(w, hcv.w, p);        \
      ARD(w, H##gg##_12) p = fdot2u(w, hd, p);           \
      ARD(w, I##gg##_0)  px = fdot2u(w, xa.x, px);       \
      ARD(w, I##gg##_1)  px = fdot2u(w, xa.y, px);       \
      ARD(w, I##gg##_2)  px = fdot2u(w, xa.z, px);       \
      ARD(w, I##gg##_3)  px = fdot2u(w, xa.w, px);       \
      ARD(w, I##gg##_4)  px = fdot2u(w, xbv.x, px);      \
      ARD(w, I##gg##_5)  px = fdot2u(w, xbv.y, px);      \
      ARD(w, I##gg##_6)  px = fdot2u(w, xbv.z, px);      \
      ARD(w, I##gg##_7)  px = fdot2u(w, xbv.w, px);      \
      ARD(w, I##gg##_8)  px = fdot2u(w, xcv.x, px);      \
      ARD(w, I##gg##_9)  px = fdot2u(w, xcv.y, px);      \
      ARD(w, I##gg##_10) px = fdot2u(w, xcv.z, px);      \
      ARD(w, I##gg##_11) px = fdot2u(w, xcv.w, px);      \
      ARD(w, I##gg##_12) px = fdot2u(w, xd, px);         \
      P = p + px;                                        \
    }
#define STEP(s)                                                               \
    {                                                                         \
      __syncthreads(); /* hb32[s&1] ready (and xh32 at s==0) */               \
      if (act) {                                                              \
        const uint4* hp = (const uint4*)(hb32 + (((s) & 1) << 6) + (q << 4)); \
        const uint4* xp = (const uint4*)(xh32 + ((s) << 6) + (q << 4));       \
        uint4 ha = hp[0], hbv = hp[1], hcv = hp[2];                           \
        unsigned hd = ((const unsigned*)hp)[12];                              \
        uint4 xa = xp[0], xbv = xp[1], xcv = xp[2];                           \
        unsigned xd = ((const unsigned*)xp)[12];                              \
        float P0, P1, P2, P3;                                                 \
        GPART(0, P0) GPART(1, P1) GPART(2, P2) GPART(3, P3)                   \
        P0 = qred(P0); P1 = qred(P1); P2 = qred(P2); P3 = qred(P3);           \
        if (q == 0) {                                                         \
          float gi = sigm(P0 + b0), gf = sigm(P1 + b1);                       \
          float gv = 2.f * sigm(2.f * (P2 + b2)) - 1.f;                       \
          float go = sigm(P3 + b3);                                           \
          c = gf * c + gi * gv;                                               \
          float h = go * (2.f * sigm(2.f * c) - 1.f);                         \
          ((unsigned short*)hb32)[((((s) + 1) & 1) << 7) + hwpos] =           \
              __builtin_bit_cast(unsigned short, (_Float16)h);                \
          if (l < NL - 1)                                                     \
            ((unsigned short*)och32)[((s) << 7) + hwpos] =                    \
                __builtin_bit_cast(unsigned short, (_Float16)fmaxf(h, 0.f));  \
          else                                                                \
            ochf[(s) * HH + j] = h;                                           \
        }                                                                     \
      }                                                                       \
    }
    STEP(0) STEP(1) STEP(2) STEP(3) STEP(4)
    STEP(5) STEP(6) STEP(7) STEP(8) STEP(9)

    __syncthreads();  // last step's publish writes visible

    if (l < NL - 1) {
      // ---- publish chunk: coalesced write + fence + flag (verbatim R8) ----
      uint4* dst = (uint4*)(xst + ((size_t)(l + 1) * TT + ch * CC) * RW);
      if (tid < 160) dst[tid] = ((const uint4*)och32)[tid];
      __syncthreads();  // all waves' global stores drained
      if (tid == 0) {
        __threadfence();
        __hip_atomic_store(flags + l * NC + ch, 1, __ATOMIC_RELEASE,
                           __HIP_MEMORY_SCOPE_AGENT);
      }
    } else {
      // ---- batched output projection for the chunk (fp32) ----
      if (act) {
        int s2 = j / 10, r = j % 10;
        const float* wrow = Wout + r * HH + q * 25;
        const float* hrow = ochf + s2 * HH + q * 25;
        float acc = 0.f;
#pragma unroll
        for (int m2 = 0; m2 < 25; ++m2) acc = fmaf(wrow[m2], hrow[m2], acc);
        acc = qred(acc);
        if (q == 0) out[(ch * CC + s2) * NOUT + r] = sigm(acc + bout[r]);
      }
    }
  }
}

extern "C" void kernel_launch(void* const* d_in, const int* in_sizes, int n_in,
                              void* d_out, int out_size, void* d_ws, size_t ws_size,
                              hipStream_t stream) {
  const float* input = (const float*)d_in[0];
  const float* Wih   = (const float*)d_in[1];
  const float* Whh   = (const float*)d_in[2];
  const float* bih   = (const float*)d_in[3];
  const float* bhh   = (const float*)d_in[4];
  const float* Wout  = (const float*)d_in[5];
  const float* bout  = (const float*)d_in[6];
  float* out = (float*)d_out;

  // ws layout (bytes):
  //   [0, 2048)        flags ((L-1)*NC = 40 ints used)
  //   [2048, 130048)   xst: NL*TT*RW dwords = 5*100*64*4 = 128000
  int* flags = (int*)d_ws;
  unsigned* xst = (unsigned*)((char*)d_ws + 2048);

  // flags must be zero at kernel start on EVERY call (graph replays included)
  hipMemsetAsync(d_ws, 0, 2048, stream);

  pack_x0<<<dim3(4), dim3(512), 0, stream>>>(input, xst);

  lstm_pipe_kernel<<<dim3(NL), dim3(NTH), 0, stream>>>(
      Wih, Whh, bih, bhh, Wout, bout, out, flags, xst);
}